// Round 3
// baseline (696.732 us; speedup 1.0000x reference)
//
#include <hip/hip_runtime.h>

#define N_NODES 50000
#define N_EDGES 800000
#define D 128

typedef __attribute__((ext_vector_type(8))) short bf16x8;
typedef __attribute__((ext_vector_type(4))) float f32x4;

__device__ __forceinline__ float bf2f(unsigned short u) {
  unsigned int v = ((unsigned int)u) << 16;
  return __uint_as_float(v);
}
__device__ __forceinline__ unsigned short f2bf(float f) {
  unsigned int u = __float_as_uint(f);
  unsigned int r = (u + 0x7fffu + ((u >> 16) & 1u)) >> 16;
  return (unsigned short)r;
}

// ---- fp32 -> bf16 cast (4 elems/thread) ---------------------------------
__global__ __launch_bounds__(256) void k_cast(const float* __restrict__ in,
                                              unsigned short* __restrict__ out,
                                              int n4) {
  int i = blockIdx.x * blockDim.x + threadIdx.x;
  if (i < n4) {
    float4 v = ((const float4*)in)[i];
    ushort4 o;
    o.x = f2bf(v.x); o.y = f2bf(v.y); o.z = f2bf(v.z); o.w = f2bf(v.w);
    ((ushort4*)out)[i] = o;
  }
}

// ---- edge dtype probe: int64 has all-zero high words --------------------
__global__ __launch_bounds__(256) void k_detect(const int* __restrict__ ei,
                                                int* __restrict__ flag) {
  __shared__ int red[256];
  int t = threadIdx.x;
  int acc = 0;
  for (int k = t; k < 65536; k += 256) acc |= ei[2 * k + 1];
  red[t] = acc;
  __syncthreads();
  for (int s = 128; s > 0; s >>= 1) {
    if (t < s) red[t] |= red[t + s];
    __syncthreads();
  }
  if (t == 0) flag[0] = (red[0] == 0) ? 1 : 0;  // 1 => int64
}

__device__ __forceinline__ int edge_at(const int* ei, int idx, int is64) {
  return is64 ? ei[2 * idx] : ei[idx];
}

// ---- CSR build ----------------------------------------------------------
__global__ __launch_bounds__(256) void k_deg(const int* __restrict__ ei,
                                             const int* __restrict__ flag,
                                             int* __restrict__ deg) {
  int is64 = flag[0];
  int e = blockIdx.x * blockDim.x + threadIdx.x;
  if (e < N_EDGES) {
    int d = edge_at(ei, N_EDGES + e, is64);
    if ((unsigned)d < N_NODES) atomicAdd(&deg[d], 1);
  }
}

__global__ __launch_bounds__(256) void k_scan(int* __restrict__ deg_cur,
                                              int* __restrict__ off) {
  __shared__ int sums[257];
  const int CHUNK = (N_NODES + 255) / 256;
  int t = threadIdx.x;
  int lo = t * CHUNK;
  int hi = min(lo + CHUNK, N_NODES);
  int s = 0;
  for (int i = lo; i < hi; ++i) s += deg_cur[i];
  sums[t] = s;
  __syncthreads();
  if (t == 0) {
    int run = 0;
    for (int i = 0; i < 256; ++i) { int v = sums[i]; sums[i] = run; run += v; }
    sums[256] = run;
  }
  __syncthreads();
  int run = sums[t];
  for (int i = lo; i < hi; ++i) {
    int v = deg_cur[i];
    off[i] = run;
    deg_cur[i] = run;  // becomes scatter cursor
    run += v;
  }
  if (t == 0) off[N_NODES] = sums[256];
}

__global__ __launch_bounds__(256) void k_scatter(const int* __restrict__ ei,
                                                 const int* __restrict__ flag,
                                                 int* __restrict__ cur,
                                                 int* __restrict__ srcs) {
  int is64 = flag[0];
  int e = blockIdx.x * blockDim.x + threadIdx.x;
  if (e < N_EDGES) {
    int d = edge_at(ei, N_EDGES + e, is64);
    int sv = edge_at(ei, e, is64);
    if ((unsigned)d < N_NODES && (unsigned)sv < N_NODES) {
      int p = atomicAdd(&cur[d], 1);
      if ((unsigned)p < N_EDGES) srcs[p] = sv;
    }
  }
}

// ---- mean aggregation: one wave/node, lane holds 2 bf16 features --------
__global__ __launch_bounds__(256) void k_agg(const unsigned short* __restrict__ feat,
                                             const int* __restrict__ off,
                                             const int* __restrict__ srcs,
                                             unsigned short* __restrict__ agg) {
  int wv = threadIdx.x >> 6;
  int lane = threadIdx.x & 63;
  int node = blockIdx.x * 4 + wv;
  if (node >= N_NODES) return;
  int b = off[node], e = off[node + 1];
  b = max(b, 0);
  e = min(max(e, b), N_EDGES);
  const unsigned int* fp = (const unsigned int*)feat;
  float a0 = 0.f, a1 = 0.f;
  for (int t = b; t < e; ++t) {
    int j = srcs[t];
    if ((unsigned)j < N_NODES) {
      unsigned int v = fp[j * 64 + lane];
      a0 += bf2f((unsigned short)(v & 0xffffu));
      a1 += bf2f((unsigned short)(v >> 16));
    }
  }
  float inv = 1.0f / (float)max(e - b, 1);
  unsigned int pair = (unsigned int)f2bf(a0 * inv) |
                      ((unsigned int)f2bf(a1 * inv) << 16);
  ((unsigned int*)agg)[node * 64 + lane] = pair;
}

// ---- GEMM: out[n,o] = sum_i A[n,i]*W1[o,i] (+ B[n,i]*W2[o,i]) + bias[o] --
// bf16 inputs/weights, fp32 accumulate; OUTF32 selects fp32 vs bf16 store.
template <bool HASB, bool OUTF32>
__global__ __launch_bounds__(256) void k_gemm(const unsigned short* A,
                                              const unsigned short* __restrict__ W1,
                                              const unsigned short* B,
                                              const unsigned short* __restrict__ W2,
                                              const float* __restrict__ bias,
                                              void* outv) {
  __shared__ unsigned short lds[128 * 136];  // pitch 136 breaks bank conflicts
  const int tid = threadIdx.x;
  const int lane = tid & 63;
  const int wv = tid >> 6;
  const int quad = lane >> 4;
  const int l16 = lane & 15;
  const int rowBase = blockIdx.x * 128;

  f32x4 acc[2][8];
#pragma unroll
  for (int rt = 0; rt < 2; ++rt)
#pragma unroll
    for (int c = 0; c < 8; ++c) acc[rt][c] = (f32x4){0.f, 0.f, 0.f, 0.f};

  const int nin = HASB ? 2 : 1;
  for (int ii = 0; ii < nin; ++ii) {
    const unsigned short* Ain = (ii == 0) ? A : B;
    const unsigned short* Win = (ii == 0) ? W1 : W2;
    __syncthreads();
    const uint4* A4 = (const uint4*)Ain;
    for (int idx = tid; idx < 128 * 16; idx += 256) {
      int r = idx >> 4, c = idx & 15;
      int gr = rowBase + r;
      uint4 v = make_uint4(0u, 0u, 0u, 0u);
      if (gr < N_NODES) v = A4[gr * 16 + c];
      *((uint4*)&lds[r * 136 + c * 8]) = v;
    }
    __syncthreads();
#pragma unroll
    for (int ks = 0; ks < 4; ++ks) {
      bf16x8 a0 = *((const bf16x8*)&lds[(wv * 32 + l16) * 136 + ks * 32 + quad * 8]);
      bf16x8 a1 = *((const bf16x8*)&lds[(wv * 32 + 16 + l16) * 136 + ks * 32 + quad * 8]);
#pragma unroll
      for (int c = 0; c < 8; ++c) {
        bf16x8 b = *((const bf16x8*)&Win[(c * 16 + l16) * 128 + ks * 32 + quad * 8]);
        acc[0][c] = __builtin_amdgcn_mfma_f32_16x16x32_bf16(a0, b, acc[0][c], 0, 0, 0);
        acc[1][c] = __builtin_amdgcn_mfma_f32_16x16x32_bf16(a1, b, acc[1][c], 0, 0, 0);
      }
    }
  }
#pragma unroll
  for (int c = 0; c < 8; ++c) {
    int col = c * 16 + l16;
    float bv = bias[col];
#pragma unroll
    for (int rt = 0; rt < 2; ++rt) {
#pragma unroll
      for (int g = 0; g < 4; ++g) {
        int row = rowBase + wv * 32 + rt * 16 + quad * 4 + g;
        if (row < N_NODES) {
          float v = acc[rt][c][g] + bv;
          if (OUTF32) ((float*)outv)[row * 128 + col] = v;
          else ((unsigned short*)outv)[row * 128 + col] = f2bf(v);
        }
      }
    }
  }
}

// ---- per-feature S1/S2 over all nodes -----------------------------------
__global__ __launch_bounds__(128) void k_stats(const unsigned short* __restrict__ pre,
                                               float* __restrict__ S) {
  int f = threadIdx.x;
  float s1 = 0.f, s2 = 0.f;
  for (int r = blockIdx.x; r < N_NODES; r += gridDim.x) {
    float v = bf2f(pre[r * 128 + f]);
    s1 += v;
    s2 += v * v;
  }
  atomicAdd(&S[f], s1);
  atomicAdd(&S[128 + f], s2);
}

// ---- GraphNorm + ReLU; RES => accumulate fp32 residual in d_out ---------
template <bool RES>
__global__ __launch_bounds__(256) void k_norm(const unsigned short* __restrict__ pre,
                                              const float* __restrict__ S,
                                              const float* __restrict__ w,
                                              const float* __restrict__ b,
                                              const float* __restrict__ a,
                                              void* outv) {
  int f = threadIdx.x & 127;
  const float invN = 1.0f / (float)N_NODES;
  float m = S[f] * invN;
  float ex2 = S[128 + f] * invN;
  float af = a[f];
  float var = ex2 - (2.f * af - af * af) * m * m;  // E[(x - a m)^2]
  var = fmaxf(var, 0.f);
  float rstd = rsqrtf(var + 1e-5f);
  float wf = w[f];
  float bv = b[f];
  float shift = af * m;
  int rowStart = blockIdx.x * 2 + (threadIdx.x >> 7);
  for (int r = rowStart; r < N_NODES; r += gridDim.x * 2) {
    int idx = r * 128 + f;
    float v = bf2f(pre[idx]);
    float o = fmaxf(wf * (v - shift) * rstd + bv, 0.f);
    if (RES) {
      float* outp = (float*)outv;
      outp[idx] = o + outp[idx];  // residual x@Wres.T + bres already there
    } else {
      ((unsigned short*)outv)[idx] = f2bf(o);
    }
  }
}

extern "C" void kernel_launch(void* const* d_in, const int* in_sizes, int n_in,
                              void* d_out, int out_size, void* d_ws, size_t ws_size,
                              hipStream_t stream) {
  const float* x = (const float*)d_in[0];
  const int* ei = (const int*)d_in[1];
  const float* Wl1 = (const float*)d_in[2];
  const float* bl1 = (const float*)d_in[3];
  const float* Wr1 = (const float*)d_in[4];
  const float* Wl2 = (const float*)d_in[5];
  const float* bl2 = (const float*)d_in[6];
  const float* Wr2 = (const float*)d_in[7];
  const float* g1w = (const float*)d_in[8];
  const float* g1b = (const float*)d_in[9];
  const float* g1a = (const float*)d_in[10];
  const float* g2w = (const float*)d_in[11];
  const float* g2b = (const float*)d_in[12];
  const float* g2a = (const float*)d_in[13];
  const float* Wres = (const float*)d_in[14];
  const float* bres = (const float*)d_in[15];

  char* w = (char*)d_ws;
  const size_t FEATB = (size_t)N_NODES * D * 2;  // 12.8 MB bf16 buffer
  // layout: xb | buf0 | agg | ip{deg,stats,flag,off,srcs,wb}
  unsigned short* xb = (unsigned short*)(w);
  unsigned short* buf0 = (unsigned short*)(w + FEATB);
  unsigned short* agg = (unsigned short*)(w + 2 * FEATB);
  char* ip = w + 3 * FEATB;
  int* deg = (int*)ip;                              // 200000 B
  float* stats = (float*)(ip + 200000);             // 2048 B (512 f)
  int* flag = (int*)(ip + 202048);                  // 16 B
  int* off = (int*)(ip + 202064);                   // 200016 B
  int* srcs = (int*)(ip + 402080);                  // 3200000 B
  unsigned short* wb = (unsigned short*)(ip + 3602080);  // 163840 B
  const size_t NEED = 3 * FEATB + 3602080 + 163840;

  float* outp = (float*)d_out;

  if (ws_size < NEED) {  // diagnostic: finite absmax (~6.19) instead of NaN
    hipMemsetAsync(d_out, 0, (size_t)out_size * 2, stream);
    return;
  }

  unsigned short* wl1b = wb;
  unsigned short* wr1b = wb + 16384;
  unsigned short* wl2b = wb + 32768;
  unsigned short* wr2b = wb + 49152;
  unsigned short* wresb = wb + 65536;

  hipMemsetAsync(ip, 0, 202064, stream);  // deg + stats + flag

  // casts
  k_cast<<<(N_NODES * D / 4 + 255) / 256, 256, 0, stream>>>(x, xb, N_NODES * D / 4);
  k_cast<<<16, 256, 0, stream>>>(Wl1, wl1b, 4096);
  k_cast<<<16, 256, 0, stream>>>(Wr1, wr1b, 4096);
  k_cast<<<16, 256, 0, stream>>>(Wl2, wl2b, 4096);
  k_cast<<<16, 256, 0, stream>>>(Wr2, wr2b, 4096);
  k_cast<<<16, 256, 0, stream>>>(Wres, wresb, 4096);

  // CSR
  k_detect<<<1, 256, 0, stream>>>(ei, flag);
  k_deg<<<(N_EDGES + 255) / 256, 256, 0, stream>>>(ei, flag, deg);
  k_scan<<<1, 256, 0, stream>>>(deg, off);
  k_scatter<<<(N_EDGES + 255) / 256, 256, 0, stream>>>(ei, flag, deg, srcs);

  const int GEMM_GRID = (N_NODES + 127) / 128;

  // layer 1
  k_agg<<<(N_NODES + 3) / 4, 256, 0, stream>>>(xb, off, srcs, agg);
  k_gemm<true, false><<<GEMM_GRID, 256, 0, stream>>>(agg, wl1b, xb, wr1b, bl1, buf0);
  // residual GEMM -> d_out (fp32), accumulated by final k_norm
  k_gemm<false, true><<<GEMM_GRID, 256, 0, stream>>>(xb, wresb, nullptr, nullptr, bres, outp);
  k_stats<<<512, 128, 0, stream>>>(buf0, stats);
  k_norm<false><<<1024, 256, 0, stream>>>(buf0, stats, g1w, g1b, g1a, buf0);

  // layer 2 (GEMM in-place into agg: each block writes only rows it consumed)
  k_agg<<<(N_NODES + 3) / 4, 256, 0, stream>>>(buf0, off, srcs, agg);
  k_gemm<true, false><<<GEMM_GRID, 256, 0, stream>>>(agg, wl2b, buf0, wr2b, bl2, agg);
  k_stats<<<512, 128, 0, stream>>>(agg, stats + 256);
  k_norm<true><<<1024, 256, 0, stream>>>(agg, stats + 256, g2w, g2b, g2a, outp);
}

// Round 4
// 395.017 us; speedup vs baseline: 1.7638x; 1.7638x over previous
//
#include <hip/hip_runtime.h>

#define N_NODES 50000
#define N_EDGES 800000
#define D 128
#define NBLK 196  // ceil(N_NODES/256)

typedef __attribute__((ext_vector_type(8))) short bf16x8;
typedef __attribute__((ext_vector_type(4))) float f32x4;

__device__ __forceinline__ float bf2f(unsigned short u) {
  unsigned int v = ((unsigned int)u) << 16;
  return __uint_as_float(v);
}
__device__ __forceinline__ unsigned short f2bf(float f) {
  unsigned int u = __float_as_uint(f);
  unsigned int r = (u + 0x7fffu + ((u >> 16) & 1u)) >> 16;
  return (unsigned short)r;
}

// ---- fp32 -> bf16 casts -------------------------------------------------
__global__ __launch_bounds__(256) void k_cast(const float* __restrict__ in,
                                              unsigned short* __restrict__ out,
                                              int n4) {
  int i = blockIdx.x * blockDim.x + threadIdx.x;
  if (i < n4) {
    float4 v = ((const float4*)in)[i];
    ushort4 o;
    o.x = f2bf(v.x); o.y = f2bf(v.y); o.z = f2bf(v.z); o.w = f2bf(v.w);
    ((ushort4*)out)[i] = o;
  }
}

// all 5 weight matrices in one dispatch (16 blocks each)
__global__ __launch_bounds__(256) void k_castw(const float* __restrict__ w0,
                                               const float* __restrict__ w1,
                                               const float* __restrict__ w2,
                                               const float* __restrict__ w3,
                                               const float* __restrict__ w4,
                                               unsigned short* __restrict__ out) {
  int m = blockIdx.x >> 4;
  int i = (blockIdx.x & 15) * 256 + threadIdx.x;  // uint4 index, 4096/matrix
  const float* src = (m == 0) ? w0 : (m == 1) ? w1 : (m == 2) ? w2 : (m == 3) ? w3 : w4;
  float4 v = ((const float4*)src)[i];
  ushort4 o;
  o.x = f2bf(v.x); o.y = f2bf(v.y); o.z = f2bf(v.z); o.w = f2bf(v.w);
  ((ushort4*)(out + m * 16384))[i] = o;
}

// ---- edge dtype probe: int64 has all-zero high words --------------------
__global__ __launch_bounds__(256) void k_detect(const int* __restrict__ ei,
                                                int* __restrict__ flag) {
  __shared__ int red[256];
  int t = threadIdx.x;
  int acc = 0;
  for (int k = t; k < 8192; k += 256) acc |= ei[2 * k + 1];
  red[t] = acc;
  __syncthreads();
  for (int s = 128; s > 0; s >>= 1) {
    if (t < s) red[t] |= red[t + s];
    __syncthreads();
  }
  if (t == 0) flag[0] = (red[0] == 0) ? 1 : 0;  // 1 => int64
}

__device__ __forceinline__ int edge_at(const int* ei, int idx, int is64) {
  return is64 ? ei[2 * idx] : ei[idx];
}

// ---- CSR build ----------------------------------------------------------
__global__ __launch_bounds__(256) void k_deg(const int* __restrict__ ei,
                                             const int* __restrict__ flag,
                                             int* __restrict__ deg) {
  int is64 = flag[0];
  int e = blockIdx.x * blockDim.x + threadIdx.x;
  if (e < N_EDGES) {
    int d = edge_at(ei, N_EDGES + e, is64);
    if ((unsigned)d < N_NODES) atomicAdd(&deg[d], 1);
  }
}

// phase 1: per-block exclusive scan + block total
__global__ __launch_bounds__(256) void k_scan1(const int* __restrict__ deg,
                                               int* __restrict__ off,
                                               int* __restrict__ bsum) {
  __shared__ int tile[256];
  int t = threadIdx.x;
  int i = blockIdx.x * 256 + t;
  int v = (i < N_NODES) ? deg[i] : 0;
  tile[t] = v;
  __syncthreads();
  for (int s = 1; s < 256; s <<= 1) {
    int add = (t >= s) ? tile[t - s] : 0;
    __syncthreads();
    tile[t] += add;
    __syncthreads();
  }
  if (i < N_NODES) off[i] = tile[t] - v;
  if (t == 255) bsum[blockIdx.x] = tile[255];
}

// phase 2: scan the 196 block sums (in LDS, trivial)
__global__ __launch_bounds__(256) void k_scan2(int* __restrict__ bsum,
                                               int* __restrict__ off) {
  __shared__ int s[256];
  int t = threadIdx.x;
  s[t] = (t < NBLK) ? bsum[t] : 0;
  __syncthreads();
  if (t == 0) {
    int run = 0;
    for (int i = 0; i < NBLK; ++i) { int v = s[i]; s[i] = run; run += v; }
    off[N_NODES] = run;
  }
  __syncthreads();
  if (t < NBLK) bsum[t] = s[t];
}

// phase 3: add block prefix; also init scatter cursor
__global__ __launch_bounds__(256) void k_scan3(int* __restrict__ off,
                                               const int* __restrict__ bsum,
                                               int* __restrict__ cur) {
  int i = blockIdx.x * 256 + threadIdx.x;
  if (i < N_NODES) {
    int o = off[i] + bsum[blockIdx.x];
    off[i] = o;
    cur[i] = o;
  }
}

__global__ __launch_bounds__(256) void k_scatter(const int* __restrict__ ei,
                                                 const int* __restrict__ flag,
                                                 int* __restrict__ cur,
                                                 int* __restrict__ srcs) {
  int is64 = flag[0];
  int e = blockIdx.x * blockDim.x + threadIdx.x;
  if (e < N_EDGES) {
    int d = edge_at(ei, N_EDGES + e, is64);
    int sv = edge_at(ei, e, is64);
    if ((unsigned)d < N_NODES && (unsigned)sv < N_NODES) {
      int p = atomicAdd(&cur[d], 1);
      if ((unsigned)p < N_EDGES) srcs[p] = sv;
    }
  }
}

// ---- mean aggregation: one wave/node, 4 edges in flight per iteration ----
// Each 16-lane group gathers one full 256B row (uint4/lane); cross-group
// reduce via shfl_xor at the end.
__device__ __forceinline__ void acc8(float* a, uint4 v) {
  a[0] += bf2f((unsigned short)(v.x & 0xffffu)); a[1] += bf2f((unsigned short)(v.x >> 16));
  a[2] += bf2f((unsigned short)(v.y & 0xffffu)); a[3] += bf2f((unsigned short)(v.y >> 16));
  a[4] += bf2f((unsigned short)(v.z & 0xffffu)); a[5] += bf2f((unsigned short)(v.z >> 16));
  a[6] += bf2f((unsigned short)(v.w & 0xffffu)); a[7] += bf2f((unsigned short)(v.w >> 16));
}

__global__ __launch_bounds__(256) void k_agg(const unsigned short* __restrict__ feat,
                                             const int* __restrict__ off,
                                             const int* __restrict__ srcs,
                                             unsigned short* __restrict__ agg) {
  int wv = threadIdx.x >> 6;
  int lane = threadIdx.x & 63;
  int node = blockIdx.x * 4 + wv;
  if (node >= N_NODES) return;
  int b = off[node], e = off[node + 1];
  int q = lane >> 4, s = lane & 15;
  const uint4* fp = (const uint4*)feat;  // one row = 16 uint4
  float a[8] = {0.f, 0.f, 0.f, 0.f, 0.f, 0.f, 0.f, 0.f};
  for (int t = b + q; t < e; t += 4) {
    int j = srcs[t];
    acc8(a, fp[j * 16 + s]);
  }
#pragma unroll
  for (int i = 0; i < 8; ++i) {
    a[i] += __shfl_xor(a[i], 16);
    a[i] += __shfl_xor(a[i], 32);
  }
  if (q == 0) {
    float inv = 1.0f / (float)max(e - b, 1);
    uint4 o;
    o.x = (unsigned)f2bf(a[0] * inv) | ((unsigned)f2bf(a[1] * inv) << 16);
    o.y = (unsigned)f2bf(a[2] * inv) | ((unsigned)f2bf(a[3] * inv) << 16);
    o.z = (unsigned)f2bf(a[4] * inv) | ((unsigned)f2bf(a[5] * inv) << 16);
    o.w = (unsigned)f2bf(a[6] * inv) | ((unsigned)f2bf(a[7] * inv) << 16);
    ((uint4*)agg)[node * 16 + s] = o;
  }
}

// ---- GEMM: out[n,o] = sum_i A[n,i]*W1[o,i] (+ B[n,i]*W2[o,i]) + bias[o] --
// bf16 in, fp32 acc; optional fused per-column S1/S2 stats (GraphNorm).
template <bool HASB, bool OUTF32, bool STATS>
__global__ __launch_bounds__(256) void k_gemm(const unsigned short* A,
                                              const unsigned short* __restrict__ W1,
                                              const unsigned short* B,
                                              const unsigned short* __restrict__ W2,
                                              const float* __restrict__ bias,
                                              void* outv,
                                              float* __restrict__ S) {
  __shared__ unsigned short lds[128 * 136];  // pitch 136 breaks bank conflicts
  __shared__ float sred[2][4][128];
  const int tid = threadIdx.x;
  const int lane = tid & 63;
  const int wv = tid >> 6;
  const int quad = lane >> 4;
  const int l16 = lane & 15;
  const int rowBase = blockIdx.x * 128;

  f32x4 acc[2][8];
#pragma unroll
  for (int rt = 0; rt < 2; ++rt)
#pragma unroll
    for (int c = 0; c < 8; ++c) acc[rt][c] = (f32x4){0.f, 0.f, 0.f, 0.f};

  const int nin = HASB ? 2 : 1;
  for (int ii = 0; ii < nin; ++ii) {
    const unsigned short* Ain = (ii == 0) ? A : B;
    const unsigned short* Win = (ii == 0) ? W1 : W2;
    __syncthreads();
    const uint4* A4 = (const uint4*)Ain;
    for (int idx = tid; idx < 128 * 16; idx += 256) {
      int r = idx >> 4, c = idx & 15;
      int gr = rowBase + r;
      uint4 v = make_uint4(0u, 0u, 0u, 0u);
      if (gr < N_NODES) v = A4[gr * 16 + c];
      *((uint4*)&lds[r * 136 + c * 8]) = v;
    }
    __syncthreads();
#pragma unroll
    for (int ks = 0; ks < 4; ++ks) {
      bf16x8 a0 = *((const bf16x8*)&lds[(wv * 32 + l16) * 136 + ks * 32 + quad * 8]);
      bf16x8 a1 = *((const bf16x8*)&lds[(wv * 32 + 16 + l16) * 136 + ks * 32 + quad * 8]);
#pragma unroll
      for (int c = 0; c < 8; ++c) {
        bf16x8 b = *((const bf16x8*)&Win[(c * 16 + l16) * 128 + ks * 32 + quad * 8]);
        acc[0][c] = __builtin_amdgcn_mfma_f32_16x16x32_bf16(a0, b, acc[0][c], 0, 0, 0);
        acc[1][c] = __builtin_amdgcn_mfma_f32_16x16x32_bf16(a1, b, acc[1][c], 0, 0, 0);
      }
    }
  }

  float p1[8], p2[8];
#pragma unroll
  for (int c = 0; c < 8; ++c) { p1[c] = 0.f; p2[c] = 0.f; }
#pragma unroll
  for (int c = 0; c < 8; ++c) {
    int col = c * 16 + l16;
    float bv = bias[col];
#pragma unroll
    for (int rt = 0; rt < 2; ++rt) {
#pragma unroll
      for (int g = 0; g < 4; ++g) {
        int row = rowBase + wv * 32 + rt * 16 + quad * 4 + g;
        if (row < N_NODES) {
          float v = acc[rt][c][g] + bv;
          if (OUTF32) ((float*)outv)[row * 128 + col] = v;
          else ((unsigned short*)outv)[row * 128 + col] = f2bf(v);
          if (STATS) { p1[c] += v; p2[c] += v * v; }
        }
      }
    }
  }
  if (STATS) {
#pragma unroll
    for (int c = 0; c < 8; ++c) {
      p1[c] += __shfl_xor(p1[c], 16); p1[c] += __shfl_xor(p1[c], 32);
      p2[c] += __shfl_xor(p2[c], 16); p2[c] += __shfl_xor(p2[c], 32);
    }
    if (quad == 0) {
#pragma unroll
      for (int c = 0; c < 8; ++c) {
        sred[0][wv][c * 16 + l16] = p1[c];
        sred[1][wv][c * 16 + l16] = p2[c];
      }
    }
    __syncthreads();
    if (tid < 128) {
      atomicAdd(&S[tid], sred[0][0][tid] + sred[0][1][tid] + sred[0][2][tid] + sred[0][3][tid]);
    } else {
      int f = tid - 128;
      atomicAdd(&S[128 + f], sred[1][0][f] + sred[1][1][f] + sred[1][2][f] + sred[1][3][f]);
    }
  }
}

// ---- GraphNorm + ReLU; RES => accumulate fp32 residual in d_out ---------
template <bool RES>
__global__ __launch_bounds__(256) void k_norm(const unsigned short* __restrict__ pre,
                                              const float* __restrict__ S,
                                              const float* __restrict__ w,
                                              const float* __restrict__ b,
                                              const float* __restrict__ a,
                                              void* outv) {
  int f = threadIdx.x & 127;
  const float invN = 1.0f / (float)N_NODES;
  float m = S[f] * invN;
  float ex2 = S[128 + f] * invN;
  float af = a[f];
  float var = ex2 - (2.f * af - af * af) * m * m;  // E[(x - a m)^2]
  var = fmaxf(var, 0.f);
  float rstd = rsqrtf(var + 1e-5f);
  float wf = w[f];
  float bv = b[f];
  float shift = af * m;
  int rowStart = blockIdx.x * 2 + (threadIdx.x >> 7);
  for (int r = rowStart; r < N_NODES; r += gridDim.x * 2) {
    int idx = r * 128 + f;
    float v = bf2f(pre[idx]);
    float o = fmaxf(wf * (v - shift) * rstd + bv, 0.f);
    if (RES) {
      float* outp = (float*)outv;
      outp[idx] = o + outp[idx];
    } else {
      ((unsigned short*)outv)[idx] = f2bf(o);
    }
  }
}

extern "C" void kernel_launch(void* const* d_in, const int* in_sizes, int n_in,
                              void* d_out, int out_size, void* d_ws, size_t ws_size,
                              hipStream_t stream) {
  const float* x = (const float*)d_in[0];
  const int* ei = (const int*)d_in[1];
  const float* Wl1 = (const float*)d_in[2];
  const float* bl1 = (const float*)d_in[3];
  const float* Wr1 = (const float*)d_in[4];
  const float* Wl2 = (const float*)d_in[5];
  const float* bl2 = (const float*)d_in[6];
  const float* Wr2 = (const float*)d_in[7];
  const float* g1w = (const float*)d_in[8];
  const float* g1b = (const float*)d_in[9];
  const float* g1a = (const float*)d_in[10];
  const float* g2w = (const float*)d_in[11];
  const float* g2b = (const float*)d_in[12];
  const float* g2a = (const float*)d_in[13];
  const float* Wres = (const float*)d_in[14];
  const float* bres = (const float*)d_in[15];

  char* w = (char*)d_ws;
  const size_t FEATB = (size_t)N_NODES * D * 2;  // 12.8 MB bf16 buffer
  unsigned short* xb = (unsigned short*)(w);
  unsigned short* buf0 = (unsigned short*)(w + FEATB);
  unsigned short* agg = (unsigned short*)(w + 2 * FEATB);
  char* ip = w + 3 * FEATB;
  int* deg = (int*)ip;                                   // 200000 B (also cursor)
  float* stats = (float*)(ip + 200000);                  // 2048 B (512 f)
  int* flag = (int*)(ip + 202048);                       // 16 B
  int* bsum = (int*)(ip + 202064);                       // 1024 B
  int* off = (int*)(ip + 203088);                        // 200016 B
  int* srcs = (int*)(ip + 403104);                       // 3200000 B
  unsigned short* wb = (unsigned short*)(ip + 3603104);  // 163840 B
  const size_t NEED = 3 * FEATB + 3603104 + 163840;

  float* outp = (float*)d_out;

  if (ws_size < NEED) {  // diagnostic: finite wrong answer instead of NaN
    hipMemsetAsync(d_out, 0, (size_t)out_size * 4, stream);
    return;
  }

  unsigned short* wl1b = wb;
  unsigned short* wr1b = wb + 16384;
  unsigned short* wl2b = wb + 32768;
  unsigned short* wr2b = wb + 49152;
  unsigned short* wresb = wb + 65536;

  hipMemsetAsync(ip, 0, 203088, stream);  // deg + stats + flag + bsum

  k_cast<<<(N_NODES * D / 4 + 255) / 256, 256, 0, stream>>>(x, xb, N_NODES * D / 4);
  k_castw<<<80, 256, 0, stream>>>(Wl1, Wr1, Wl2, Wr2, Wres, wb);

  // CSR
  k_detect<<<1, 256, 0, stream>>>(ei, flag);
  k_deg<<<(N_EDGES + 255) / 256, 256, 0, stream>>>(ei, flag, deg);
  k_scan1<<<NBLK, 256, 0, stream>>>(deg, off, bsum);
  k_scan2<<<1, 256, 0, stream>>>(bsum, off);
  k_scan3<<<NBLK, 256, 0, stream>>>(off, bsum, deg);
  k_scatter<<<(N_EDGES + 255) / 256, 256, 0, stream>>>(ei, flag, deg, srcs);

  const int GEMM_GRID = (N_NODES + 127) / 128;

  // layer 1
  k_agg<<<(N_NODES + 3) / 4, 256, 0, stream>>>(xb, off, srcs, agg);
  k_gemm<true, false, true><<<GEMM_GRID, 256, 0, stream>>>(agg, wl1b, xb, wr1b, bl1, buf0, stats);
  k_gemm<false, true, false><<<GEMM_GRID, 256, 0, stream>>>(xb, wresb, nullptr, nullptr, bres, outp, nullptr);
  k_norm<false><<<1024, 256, 0, stream>>>(buf0, stats, g1w, g1b, g1a, buf0);

  // layer 2 (GEMM in-place into agg: blocks only write rows they consumed)
  k_agg<<<(N_NODES + 3) / 4, 256, 0, stream>>>(buf0, off, srcs, agg);
  k_gemm<true, false, true><<<GEMM_GRID, 256, 0, stream>>>(agg, wl2b, buf0, wr2b, bl2, agg, stats + 256);
  k_norm<true><<<1024, 256, 0, stream>>>(agg, stats + 256, g2w, g2b, g2a, outp);
}

// Round 5
// 357.913 us; speedup vs baseline: 1.9467x; 1.1037x over previous
//
#include <hip/hip_runtime.h>

#define N_NODES 50000
#define N_EDGES 800000
#define D 128
#define NBKT 98       // ceil(50000/512) buckets of 512 dst nodes
#define BKT_SHIFT 9
#define EPB 8192      // edges per binning block (98 blocks)

typedef __attribute__((ext_vector_type(8))) short bf16x8;
typedef __attribute__((ext_vector_type(4))) float f32x4;

__device__ __forceinline__ float bf2f(unsigned short u) {
  unsigned int v = ((unsigned int)u) << 16;
  return __uint_as_float(v);
}
__device__ __forceinline__ unsigned short f2bf(float f) {
  unsigned int u = __float_as_uint(f);
  unsigned int r = (u + 0x7fffu + ((u >> 16) & 1u)) >> 16;
  return (unsigned short)r;
}

// ---- fp32 -> bf16 casts -------------------------------------------------
__global__ __launch_bounds__(256) void k_cast(const float* __restrict__ in,
                                              unsigned short* __restrict__ out,
                                              int n4) {
  int i = blockIdx.x * blockDim.x + threadIdx.x;
  if (i < n4) {
    float4 v = ((const float4*)in)[i];
    ushort4 o;
    o.x = f2bf(v.x); o.y = f2bf(v.y); o.z = f2bf(v.z); o.w = f2bf(v.w);
    ((ushort4*)out)[i] = o;
  }
}

__global__ __launch_bounds__(256) void k_castw(const float* __restrict__ w0,
                                               const float* __restrict__ w1,
                                               const float* __restrict__ w2,
                                               const float* __restrict__ w3,
                                               const float* __restrict__ w4,
                                               unsigned short* __restrict__ out) {
  int m = blockIdx.x >> 4;
  int i = (blockIdx.x & 15) * 256 + threadIdx.x;  // uint4 index, 4096/matrix
  const float* src = (m == 0) ? w0 : (m == 1) ? w1 : (m == 2) ? w2 : (m == 3) ? w3 : w4;
  float4 v = ((const float4*)src)[i];
  ushort4 o;
  o.x = f2bf(v.x); o.y = f2bf(v.y); o.z = f2bf(v.z); o.w = f2bf(v.w);
  ((ushort4*)(out + m * 16384))[i] = o;
}

// ---- edge dtype probe: int64 has all-zero high words --------------------
__global__ __launch_bounds__(256) void k_detect(const int* __restrict__ ei,
                                                int* __restrict__ flag) {
  __shared__ int red[256];
  int t = threadIdx.x;
  int acc = 0;
  for (int k = t; k < 8192; k += 256) acc |= ei[2 * k + 1];
  red[t] = acc;
  __syncthreads();
  for (int s = 128; s > 0; s >>= 1) {
    if (t < s) red[t] |= red[t + s];
    __syncthreads();
  }
  if (t == 0) flag[0] = (red[0] == 0) ? 1 : 0;  // 1 => int64
}

__device__ __forceinline__ int edge_at(const int* ei, int idx, int is64) {
  return is64 ? ei[2 * idx] : ei[idx];
}

// ---- bucketed CSR build -------------------------------------------------
// A0: per-block LDS histogram of bucket counts -> 98 global atomics/block
__global__ __launch_bounds__(256) void k_binA0(const int* __restrict__ ei,
                                               const int* __restrict__ flag,
                                               int* __restrict__ bcnt) {
  __shared__ int h[128];
  int t = threadIdx.x;
  if (t < 128) h[t] = 0;
  __syncthreads();
  int is64 = flag[0];
  int start = blockIdx.x * EPB;
  int end = min(start + EPB, N_EDGES);
  for (int e = start + t; e < end; e += 256) {
    int d = edge_at(ei, N_EDGES + e, is64);
    if ((unsigned)d < N_NODES) atomicAdd(&h[d >> BKT_SHIFT], 1);
  }
  __syncthreads();
  if (t < NBKT && h[t]) atomicAdd(&bcnt[t], h[t]);
}

// scan 98 bucket totals -> bases + cursors; off[N] = total
__global__ __launch_bounds__(128) void k_scanS(const int* __restrict__ bcnt,
                                               int* __restrict__ bbase,
                                               int* __restrict__ cursor,
                                               int* __restrict__ off) {
  __shared__ int s[NBKT + 1];
  int t = threadIdx.x;
  if (t < NBKT) s[t] = bcnt[t];
  __syncthreads();
  if (t == 0) {
    int run = 0;
    for (int i = 0; i < NBKT; ++i) { int v = s[i]; s[i] = run; run += v; }
    s[NBKT] = run;
  }
  __syncthreads();
  if (t < NBKT) { bbase[t] = s[t]; cursor[t] = s[t]; }
  if (t == 0) { bbase[NBKT] = s[NBKT]; off[N_NODES] = s[NBKT]; }
}

// A1: re-read edges, reserve per-block bucket space (98 atomics/block),
// write packed (src | dst<<16) in contiguous per-bucket runs.
__global__ __launch_bounds__(256) void k_binA1(const int* __restrict__ ei,
                                               const int* __restrict__ flag,
                                               int* __restrict__ cursor,
                                               unsigned int* __restrict__ binned) {
  __shared__ int h[128];
  __shared__ int resv[128];
  int t = threadIdx.x;
  if (t < 128) h[t] = 0;
  __syncthreads();
  int is64 = flag[0];
  int start = blockIdx.x * EPB;
  int end = min(start + EPB, N_EDGES);
  for (int e = start + t; e < end; e += 256) {
    int d = edge_at(ei, N_EDGES + e, is64);
    if ((unsigned)d < N_NODES) atomicAdd(&h[d >> BKT_SHIFT], 1);
  }
  __syncthreads();
  if (t < NBKT) {
    resv[t] = h[t] ? atomicAdd(&cursor[t], h[t]) : 0;
    h[t] = 0;
  }
  __syncthreads();
  for (int e = start + t; e < end; e += 256) {
    int d = edge_at(ei, N_EDGES + e, is64);
    int sv = edge_at(ei, e, is64);
    if ((unsigned)d < N_NODES && (unsigned)sv < N_NODES) {
      int b = d >> BKT_SHIFT;
      int r = atomicAdd(&h[b], 1);
      binned[resv[b] + r] = (unsigned)sv | ((unsigned)d << 16);
    }
  }
}

// pass2: one block per bucket. LDS hist(512) -> off[] directly; then scatter
// srcs (ushort) into the bucket's L2-resident window.
__global__ __launch_bounds__(256) void k_pass2(const int* __restrict__ bbase,
                                               const unsigned int* __restrict__ binned,
                                               int* __restrict__ off,
                                               unsigned short* __restrict__ srcs) {
  __shared__ int h[512];
  __shared__ int ps[256];
  __shared__ int sc[512];
  int t = threadIdx.x;
  int b = blockIdx.x;
  int base = bbase[b];
  int cnt = bbase[b + 1] - base;
  h[t] = 0; h[t + 256] = 0;
  __syncthreads();
  for (int e = base + t; e < base + cnt; e += 256) {
    unsigned v = binned[e];
    int l = (int)(v >> 16) - (b << BKT_SHIFT);
    atomicAdd(&h[l], 1);
  }
  __syncthreads();
  // exclusive scan over 512 counters (pairs + Hillis-Steele over 256)
  int pair = h[2 * t] + h[2 * t + 1];
  ps[t] = pair;
  __syncthreads();
  for (int s = 1; s < 256; s <<= 1) {
    int add = (t >= s) ? ps[t - s] : 0;
    __syncthreads();
    ps[t] += add;
    __syncthreads();
  }
  int pexcl = ps[t] - pair;
  sc[2 * t] = pexcl;
  sc[2 * t + 1] = pexcl + h[2 * t];
  __syncthreads();
  h[t] = 0; h[t + 256] = 0;  // become rank counters
  // write off
  {
    int n0 = (b << BKT_SHIFT) + t;
    int n1 = n0 + 256;
    if (n0 < N_NODES) off[n0] = base + sc[t];
    if (n1 < N_NODES && t + 256 < 512) off[n1] = base + sc[t + 256];
  }
  __syncthreads();
  for (int e = base + t; e < base + cnt; e += 256) {
    unsigned v = binned[e];
    int l = (int)(v >> 16) - (b << BKT_SHIFT);
    int r = atomicAdd(&h[l], 1);
    srcs[base + sc[l] + r] = (unsigned short)(v & 0xffffu);
  }
}

// ---- mean aggregation: one wave/node, 4 edges in flight per iteration ----
__device__ __forceinline__ void acc8(float* a, uint4 v) {
  a[0] += bf2f((unsigned short)(v.x & 0xffffu)); a[1] += bf2f((unsigned short)(v.x >> 16));
  a[2] += bf2f((unsigned short)(v.y & 0xffffu)); a[3] += bf2f((unsigned short)(v.y >> 16));
  a[4] += bf2f((unsigned short)(v.z & 0xffffu)); a[5] += bf2f((unsigned short)(v.z >> 16));
  a[6] += bf2f((unsigned short)(v.w & 0xffffu)); a[7] += bf2f((unsigned short)(v.w >> 16));
}

__global__ __launch_bounds__(256) void k_agg(const unsigned short* __restrict__ feat,
                                             const int* __restrict__ off,
                                             const unsigned short* __restrict__ srcs,
                                             unsigned short* __restrict__ agg) {
  int wv = threadIdx.x >> 6;
  int lane = threadIdx.x & 63;
  int node = blockIdx.x * 4 + wv;
  if (node >= N_NODES) return;
  int b = off[node], e = off[node + 1];
  b = max(b, 0);
  e = min(max(e, b), N_EDGES);
  int q = lane >> 4, s = lane & 15;
  const uint4* fp = (const uint4*)feat;  // one row = 16 uint4
  float a[8] = {0.f, 0.f, 0.f, 0.f, 0.f, 0.f, 0.f, 0.f};
  for (int t = b + q; t < e; t += 4) {
    unsigned j = srcs[t];
    acc8(a, fp[j * 16 + s]);
  }
#pragma unroll
  for (int i = 0; i < 8; ++i) {
    a[i] += __shfl_xor(a[i], 16);
    a[i] += __shfl_xor(a[i], 32);
  }
  if (q == 0) {
    float inv = 1.0f / (float)max(e - b, 1);
    uint4 o;
    o.x = (unsigned)f2bf(a[0] * inv) | ((unsigned)f2bf(a[1] * inv) << 16);
    o.y = (unsigned)f2bf(a[2] * inv) | ((unsigned)f2bf(a[3] * inv) << 16);
    o.z = (unsigned)f2bf(a[4] * inv) | ((unsigned)f2bf(a[5] * inv) << 16);
    o.w = (unsigned)f2bf(a[6] * inv) | ((unsigned)f2bf(a[7] * inv) << 16);
    ((uint4*)agg)[node * 16 + s] = o;
  }
}

// ---- GEMM: out[n,o] = sum_i A[n,i]*W1[o,i] (+ B[n,i]*W2[o,i]) + bias[o] --
template <bool HASB, bool OUTF32, bool STATS>
__global__ __launch_bounds__(256) void k_gemm(const unsigned short* A,
                                              const unsigned short* __restrict__ W1,
                                              const unsigned short* B,
                                              const unsigned short* __restrict__ W2,
                                              const float* __restrict__ bias,
                                              void* outv,
                                              float* __restrict__ S) {
  __shared__ unsigned short lds[128 * 136];  // pitch 136 breaks bank conflicts
  __shared__ float sred[2][4][128];
  const int tid = threadIdx.x;
  const int lane = tid & 63;
  const int wv = tid >> 6;
  const int quad = lane >> 4;
  const int l16 = lane & 15;
  const int rowBase = blockIdx.x * 128;

  f32x4 acc[2][8];
#pragma unroll
  for (int rt = 0; rt < 2; ++rt)
#pragma unroll
    for (int c = 0; c < 8; ++c) acc[rt][c] = (f32x4){0.f, 0.f, 0.f, 0.f};

  const int nin = HASB ? 2 : 1;
  for (int ii = 0; ii < nin; ++ii) {
    const unsigned short* Ain = (ii == 0) ? A : B;
    const unsigned short* Win = (ii == 0) ? W1 : W2;
    __syncthreads();
    const uint4* A4 = (const uint4*)Ain;
    for (int idx = tid; idx < 128 * 16; idx += 256) {
      int r = idx >> 4, c = idx & 15;
      int gr = rowBase + r;
      uint4 v = make_uint4(0u, 0u, 0u, 0u);
      if (gr < N_NODES) v = A4[gr * 16 + c];
      *((uint4*)&lds[r * 136 + c * 8]) = v;
    }
    __syncthreads();
#pragma unroll
    for (int ks = 0; ks < 4; ++ks) {
      bf16x8 a0 = *((const bf16x8*)&lds[(wv * 32 + l16) * 136 + ks * 32 + quad * 8]);
      bf16x8 a1 = *((const bf16x8*)&lds[(wv * 32 + 16 + l16) * 136 + ks * 32 + quad * 8]);
#pragma unroll
      for (int c = 0; c < 8; ++c) {
        bf16x8 b = *((const bf16x8*)&Win[(c * 16 + l16) * 128 + ks * 32 + quad * 8]);
        acc[0][c] = __builtin_amdgcn_mfma_f32_16x16x32_bf16(a0, b, acc[0][c], 0, 0, 0);
        acc[1][c] = __builtin_amdgcn_mfma_f32_16x16x32_bf16(a1, b, acc[1][c], 0, 0, 0);
      }
    }
  }

  float p1[8], p2[8];
#pragma unroll
  for (int c = 0; c < 8; ++c) { p1[c] = 0.f; p2[c] = 0.f; }
#pragma unroll
  for (int c = 0; c < 8; ++c) {
    int col = c * 16 + l16;
    float bv = bias[col];
#pragma unroll
    for (int rt = 0; rt < 2; ++rt) {
#pragma unroll
      for (int g = 0; g < 4; ++g) {
        int row = rowBase + wv * 32 + rt * 16 + quad * 4 + g;
        if (row < N_NODES) {
          float v = acc[rt][c][g] + bv;
          if (OUTF32) ((float*)outv)[row * 128 + col] = v;
          else ((unsigned short*)outv)[row * 128 + col] = f2bf(v);
          if (STATS) { p1[c] += v; p2[c] += v * v; }
        }
      }
    }
  }
  if (STATS) {
#pragma unroll
    for (int c = 0; c < 8; ++c) {
      p1[c] += __shfl_xor(p1[c], 16); p1[c] += __shfl_xor(p1[c], 32);
      p2[c] += __shfl_xor(p2[c], 16); p2[c] += __shfl_xor(p2[c], 32);
    }
    if (quad == 0) {
#pragma unroll
      for (int c = 0; c < 8; ++c) {
        sred[0][wv][c * 16 + l16] = p1[c];
        sred[1][wv][c * 16 + l16] = p2[c];
      }
    }
    __syncthreads();
    if (tid < 128) {
      atomicAdd(&S[tid], sred[0][0][tid] + sred[0][1][tid] + sred[0][2][tid] + sred[0][3][tid]);
    } else {
      int f = tid - 128;
      atomicAdd(&S[128 + f], sred[1][0][f] + sred[1][1][f] + sred[1][2][f] + sred[1][3][f]);
    }
  }
}

// ---- GraphNorm + ReLU; RES => accumulate fp32 residual in d_out ---------
template <bool RES>
__global__ __launch_bounds__(256) void k_norm(const unsigned short* __restrict__ pre,
                                              const float* __restrict__ S,
                                              const float* __restrict__ w,
                                              const float* __restrict__ b,
                                              const float* __restrict__ a,
                                              void* outv) {
  int f = threadIdx.x & 127;
  const float invN = 1.0f / (float)N_NODES;
  float m = S[f] * invN;
  float ex2 = S[128 + f] * invN;
  float af = a[f];
  float var = ex2 - (2.f * af - af * af) * m * m;  // E[(x - a m)^2]
  var = fmaxf(var, 0.f);
  float rstd = rsqrtf(var + 1e-5f);
  float wf = w[f];
  float bv = b[f];
  float shift = af * m;
  int rowStart = blockIdx.x * 2 + (threadIdx.x >> 7);
  for (int r = rowStart; r < N_NODES; r += gridDim.x * 2) {
    int idx = r * 128 + f;
    float v = bf2f(pre[idx]);
    float o = fmaxf(wf * (v - shift) * rstd + bv, 0.f);
    if (RES) {
      float* outp = (float*)outv;
      outp[idx] = o + outp[idx];
    } else {
      ((unsigned short*)outv)[idx] = f2bf(o);
    }
  }
}

extern "C" void kernel_launch(void* const* d_in, const int* in_sizes, int n_in,
                              void* d_out, int out_size, void* d_ws, size_t ws_size,
                              hipStream_t stream) {
  const float* x = (const float*)d_in[0];
  const int* ei = (const int*)d_in[1];
  const float* Wl1 = (const float*)d_in[2];
  const float* bl1 = (const float*)d_in[3];
  const float* Wr1 = (const float*)d_in[4];
  const float* Wl2 = (const float*)d_in[5];
  const float* bl2 = (const float*)d_in[6];
  const float* Wr2 = (const float*)d_in[7];
  const float* g1w = (const float*)d_in[8];
  const float* g1b = (const float*)d_in[9];
  const float* g1a = (const float*)d_in[10];
  const float* g2w = (const float*)d_in[11];
  const float* g2b = (const float*)d_in[12];
  const float* g2a = (const float*)d_in[13];
  const float* Wres = (const float*)d_in[14];
  const float* bres = (const float*)d_in[15];

  char* w = (char*)d_ws;
  const size_t FEATB = (size_t)N_NODES * D * 2;  // 12.8 MB bf16 buffer
  unsigned short* xb = (unsigned short*)(w);
  unsigned short* buf0 = (unsigned short*)(w + FEATB);
  unsigned short* agg = (unsigned short*)(w + 2 * FEATB);
  char* ip = w + 3 * FEATB;
  int* bcnt = (int*)ip;                                  // 512 B   (zeroed)
  float* stats = (float*)(ip + 512);                     // 2048 B  (zeroed)
  int* flag = (int*)(ip + 2560);                         // 16 B
  int* bbase = (int*)(ip + 2576);                        // 512 B (99 used)
  int* cursor = (int*)(ip + 3088);                       // 512 B
  int* off = (int*)(ip + 3600);                          // 200016 B
  unsigned short* srcs = (unsigned short*)(ip + 203616); // 1.6 MB
  unsigned short* wb = (unsigned short*)(ip + 1803616);  // 163840 B
  const size_t NEED = 3 * FEATB + 1967456;
  // binned (3.2 MB) aliases agg (12.8 MB): used only before first k_agg
  unsigned int* binned = (unsigned int*)agg;

  float* outp = (float*)d_out;

  if (ws_size < NEED) {  // diagnostic: finite wrong answer instead of NaN
    hipMemsetAsync(d_out, 0, (size_t)out_size * 4, stream);
    return;
  }

  unsigned short* wl1b = wb;
  unsigned short* wr1b = wb + 16384;
  unsigned short* wl2b = wb + 32768;
  unsigned short* wr2b = wb + 49152;
  unsigned short* wresb = wb + 65536;

  hipMemsetAsync(ip, 0, 2560, stream);  // bcnt + stats

  k_cast<<<(N_NODES * D / 4 + 255) / 256, 256, 0, stream>>>(x, xb, N_NODES * D / 4);
  k_castw<<<80, 256, 0, stream>>>(Wl1, Wr1, Wl2, Wr2, Wres, wb);

  // bucketed CSR build
  k_detect<<<1, 256, 0, stream>>>(ei, flag);
  k_binA0<<<NBKT, 256, 0, stream>>>(ei, flag, bcnt);
  k_scanS<<<1, 128, 0, stream>>>(bcnt, bbase, cursor, off);
  k_binA1<<<NBKT, 256, 0, stream>>>(ei, flag, cursor, binned);
  k_pass2<<<NBKT, 256, 0, stream>>>(bbase, binned, off, srcs);

  const int GEMM_GRID = (N_NODES + 127) / 128;

  // layer 1
  k_agg<<<(N_NODES + 3) / 4, 256, 0, stream>>>(xb, off, srcs, agg);
  k_gemm<true, false, true><<<GEMM_GRID, 256, 0, stream>>>(agg, wl1b, xb, wr1b, bl1, buf0, stats);
  k_gemm<false, true, false><<<GEMM_GRID, 256, 0, stream>>>(xb, wresb, nullptr, nullptr, bres, outp, nullptr);
  k_norm<false><<<1024, 256, 0, stream>>>(buf0, stats, g1w, g1b, g1a, buf0);

  // layer 2 (GEMM in-place into agg: blocks only write rows they consumed)
  k_agg<<<(N_NODES + 3) / 4, 256, 0, stream>>>(buf0, off, srcs, agg);
  k_gemm<true, false, true><<<GEMM_GRID, 256, 0, stream>>>(agg, wl2b, buf0, wr2b, bl2, agg, stats + 256);
  k_norm<true><<<1024, 256, 0, stream>>>(agg, stats + 256, g2w, g2b, g2a, outp);
}

// Round 6
// 352.534 us; speedup vs baseline: 1.9764x; 1.0153x over previous
//
#include <hip/hip_runtime.h>

#define N_NODES 50000
#define N_EDGES 800000
#define D 128
#define NBKT 98       // ceil(50000/512) buckets of 512 dst nodes
#define BKT_SHIFT 9
#define EPB 8192      // edges per binning block (98 blocks)

typedef __attribute__((ext_vector_type(8))) short bf16x8;
typedef __attribute__((ext_vector_type(4))) float f32x4;

__device__ __forceinline__ float bf2f(unsigned short u) {
  unsigned int v = ((unsigned int)u) << 16;
  return __uint_as_float(v);
}
__device__ __forceinline__ unsigned short f2bf(float f) {
  unsigned int u = __float_as_uint(f);
  unsigned int r = (u + 0x7fffu + ((u >> 16) & 1u)) >> 16;
  return (unsigned short)r;
}

// ---- fp32 -> bf16 casts -------------------------------------------------
__global__ __launch_bounds__(256) void k_cast(const float* __restrict__ in,
                                              unsigned short* __restrict__ out,
                                              int n4) {
  int i = blockIdx.x * blockDim.x + threadIdx.x;
  if (i < n4) {
    float4 v = ((const float4*)in)[i];
    ushort4 o;
    o.x = f2bf(v.x); o.y = f2bf(v.y); o.z = f2bf(v.z); o.w = f2bf(v.w);
    ((ushort4*)out)[i] = o;
  }
}

__global__ __launch_bounds__(256) void k_castw(const float* __restrict__ w0,
                                               const float* __restrict__ w1,
                                               const float* __restrict__ w2,
                                               const float* __restrict__ w3,
                                               const float* __restrict__ w4,
                                               unsigned short* __restrict__ out) {
  int m = blockIdx.x >> 4;
  int i = (blockIdx.x & 15) * 256 + threadIdx.x;  // uint4 index, 4096/matrix
  const float* src = (m == 0) ? w0 : (m == 1) ? w1 : (m == 2) ? w2 : (m == 3) ? w3 : w4;
  float4 v = ((const float4*)src)[i];
  ushort4 o;
  o.x = f2bf(v.x); o.y = f2bf(v.y); o.z = f2bf(v.z); o.w = f2bf(v.w);
  ((ushort4*)(out + m * 16384))[i] = o;
}

// ---- edge dtype probe + zero-init of bcnt/stats -------------------------
__global__ __launch_bounds__(256) void k_detect(const int* __restrict__ ei,
                                                int* __restrict__ flag,
                                                int* __restrict__ bcnt,
                                                float* __restrict__ stats) {
  __shared__ int red[256];
  int t = threadIdx.x;
  if (t < 128) bcnt[t] = 0;
  stats[t] = 0.f;
  stats[t + 256] = 0.f;
  int acc = 0;
  for (int k = t; k < 8192; k += 256) acc |= ei[2 * k + 1];
  red[t] = acc;
  __syncthreads();
  for (int s = 128; s > 0; s >>= 1) {
    if (t < s) red[t] |= red[t + s];
    __syncthreads();
  }
  if (t == 0) flag[0] = (red[0] == 0) ? 1 : 0;  // 1 => int64
}

__device__ __forceinline__ int edge_at(const int* ei, int idx, int is64) {
  return is64 ? ei[2 * idx] : ei[idx];
}

// ---- bucketed CSR build -------------------------------------------------
__global__ __launch_bounds__(256) void k_binA0(const int* __restrict__ ei,
                                               const int* __restrict__ flag,
                                               int* __restrict__ bcnt) {
  __shared__ int h[128];
  int t = threadIdx.x;
  if (t < 128) h[t] = 0;
  __syncthreads();
  int is64 = flag[0];
  int start = blockIdx.x * EPB;
  int end = min(start + EPB, N_EDGES);
  for (int e = start + t; e < end; e += 256) {
    int d = edge_at(ei, N_EDGES + e, is64);
    if ((unsigned)d < N_NODES) atomicAdd(&h[d >> BKT_SHIFT], 1);
  }
  __syncthreads();
  if (t < NBKT && h[t]) atomicAdd(&bcnt[t], h[t]);
}

__global__ __launch_bounds__(128) void k_scanS(const int* __restrict__ bcnt,
                                               int* __restrict__ bbase,
                                               int* __restrict__ cursor,
                                               int* __restrict__ off) {
  __shared__ int s[NBKT + 1];
  int t = threadIdx.x;
  if (t < NBKT) s[t] = bcnt[t];
  __syncthreads();
  if (t == 0) {
    int run = 0;
    for (int i = 0; i < NBKT; ++i) { int v = s[i]; s[i] = run; run += v; }
    s[NBKT] = run;
  }
  __syncthreads();
  if (t < NBKT) { bbase[t] = s[t]; cursor[t] = s[t]; }
  if (t == 0) { bbase[NBKT] = s[NBKT]; off[N_NODES] = s[NBKT]; }
}

__global__ __launch_bounds__(256) void k_binA1(const int* __restrict__ ei,
                                               const int* __restrict__ flag,
                                               int* __restrict__ cursor,
                                               unsigned int* __restrict__ binned) {
  __shared__ int h[128];
  __shared__ int resv[128];
  int t = threadIdx.x;
  if (t < 128) h[t] = 0;
  __syncthreads();
  int is64 = flag[0];
  int start = blockIdx.x * EPB;
  int end = min(start + EPB, N_EDGES);
  for (int e = start + t; e < end; e += 256) {
    int d = edge_at(ei, N_EDGES + e, is64);
    if ((unsigned)d < N_NODES) atomicAdd(&h[d >> BKT_SHIFT], 1);
  }
  __syncthreads();
  if (t < NBKT) {
    resv[t] = h[t] ? atomicAdd(&cursor[t], h[t]) : 0;
    h[t] = 0;
  }
  __syncthreads();
  for (int e = start + t; e < end; e += 256) {
    int d = edge_at(ei, N_EDGES + e, is64);
    int sv = edge_at(ei, e, is64);
    if ((unsigned)d < N_NODES && (unsigned)sv < N_NODES) {
      int b = d >> BKT_SHIFT;
      int r = atomicAdd(&h[b], 1);
      binned[resv[b] + r] = (unsigned)sv | ((unsigned)d << 16);
    }
  }
}

__global__ __launch_bounds__(256) void k_pass2(const int* __restrict__ bbase,
                                               const unsigned int* __restrict__ binned,
                                               int* __restrict__ off,
                                               unsigned short* __restrict__ srcs) {
  __shared__ int h[512];
  __shared__ int ps[256];
  __shared__ int sc[512];
  int t = threadIdx.x;
  int b = blockIdx.x;
  int base = bbase[b];
  int cnt = bbase[b + 1] - base;
  h[t] = 0; h[t + 256] = 0;
  __syncthreads();
  for (int e = base + t; e < base + cnt; e += 256) {
    unsigned v = binned[e];
    int l = (int)(v >> 16) - (b << BKT_SHIFT);
    atomicAdd(&h[l], 1);
  }
  __syncthreads();
  int pair = h[2 * t] + h[2 * t + 1];
  ps[t] = pair;
  __syncthreads();
  for (int s = 1; s < 256; s <<= 1) {
    int add = (t >= s) ? ps[t - s] : 0;
    __syncthreads();
    ps[t] += add;
    __syncthreads();
  }
  int pexcl = ps[t] - pair;
  sc[2 * t] = pexcl;
  sc[2 * t + 1] = pexcl + h[2 * t];
  __syncthreads();
  h[t] = 0; h[t + 256] = 0;
  {
    int n0 = (b << BKT_SHIFT) + t;
    int n1 = n0 + 256;
    if (n0 < N_NODES) off[n0] = base + sc[t];
    if (n1 < N_NODES) off[n1] = base + sc[t + 256];
  }
  __syncthreads();
  for (int e = base + t; e < base + cnt; e += 256) {
    unsigned v = binned[e];
    int l = (int)(v >> 16) - (b << BKT_SHIFT);
    int r = atomicAdd(&h[l], 1);
    srcs[base + sc[l] + r] = (unsigned short)(v & 0xffffu);
  }
}

// ---- mean aggregation ----------------------------------------------------
// One wave/node. Wave preloads up to 64 edge indices coalesced, distributes
// via __shfl; each 16-lane group gathers one 256B row/iteration. NORM applies
// layer-1 GraphNorm+ReLU (per-feature affine) to gathered values on the fly.
template <bool NORM>
__global__ __launch_bounds__(256) void k_agg(const unsigned short* __restrict__ feat,
                                             const int* __restrict__ off,
                                             const unsigned short* __restrict__ srcs,
                                             const float* __restrict__ Sin,
                                             const float* __restrict__ gw,
                                             const float* __restrict__ gb,
                                             const float* __restrict__ ga,
                                             unsigned short* __restrict__ agg) {
  int wv = threadIdx.x >> 6;
  int lane = threadIdx.x & 63;
  int node = blockIdx.x * 4 + wv;
  if (node >= N_NODES) return;
  int q = lane >> 4, s = lane & 15;

  float sc[8], bt[8];
  if (NORM) {
    const float invN = 1.0f / (float)N_NODES;
#pragma unroll
    for (int i = 0; i < 8; ++i) {
      int f = s * 8 + i;
      float m = Sin[f] * invN;
      float ex2 = Sin[128 + f] * invN;
      float af = ga[f];
      float var = fmaxf(ex2 - (2.f * af - af * af) * m * m, 0.f);
      float rstd = rsqrtf(var + 1e-5f);
      sc[i] = gw[f] * rstd;
      bt[i] = gb[f] - sc[i] * af * m;
    }
  }

  int b = off[node], e = off[node + 1];
  const uint4* fp = (const uint4*)feat;
  float a[8] = {0.f, 0.f, 0.f, 0.f, 0.f, 0.f, 0.f, 0.f};
  for (int cb = b; cb < e; cb += 64) {
    int n = min(64, e - cb);
    int jv = (lane < n) ? (int)srcs[cb + lane] : 0;
    int kmax = (n + 3) >> 2;
    for (int k = 0; k < kmax; ++k) {
      int t = 4 * k + q;
      int j = __shfl(jv, t);
      uint4 v = fp[j * 16 + s];
      if (t < n) {
        unsigned int* pv = (unsigned int*)&v;
#pragma unroll
        for (int h = 0; h < 4; ++h) {
          float lo = bf2f((unsigned short)(pv[h] & 0xffffu));
          float hi = bf2f((unsigned short)(pv[h] >> 16));
          if (NORM) {
            a[2 * h] += fmaxf(sc[2 * h] * lo + bt[2 * h], 0.f);
            a[2 * h + 1] += fmaxf(sc[2 * h + 1] * hi + bt[2 * h + 1], 0.f);
          } else {
            a[2 * h] += lo;
            a[2 * h + 1] += hi;
          }
        }
      }
    }
  }
#pragma unroll
  for (int i = 0; i < 8; ++i) {
    a[i] += __shfl_xor(a[i], 16);
    a[i] += __shfl_xor(a[i], 32);
  }
  if (q == 0) {
    float inv = 1.0f / (float)max(e - b, 1);
    uint4 o;
    o.x = (unsigned)f2bf(a[0] * inv) | ((unsigned)f2bf(a[1] * inv) << 16);
    o.y = (unsigned)f2bf(a[2] * inv) | ((unsigned)f2bf(a[3] * inv) << 16);
    o.z = (unsigned)f2bf(a[4] * inv) | ((unsigned)f2bf(a[5] * inv) << 16);
    o.w = (unsigned)f2bf(a[6] * inv) | ((unsigned)f2bf(a[7] * inv) << 16);
    ((uint4*)agg)[node * 16 + s] = o;
  }
}

// ---- GEMM: out = A@W1^T + B@W2^T + bias; fused stats; optional fused
// residual (B@Wres^T + bres -> fp32 outres); optional norm of B at staging.
template <bool FUSERES, bool NORMB>
__global__ __launch_bounds__(256) void k_gemm(const unsigned short* A,
                                              const unsigned short* __restrict__ W1,
                                              const unsigned short* B,
                                              const unsigned short* __restrict__ W2,
                                              const unsigned short* __restrict__ Wres,
                                              const float* __restrict__ bias,
                                              void* outv,
                                              float* __restrict__ outres,
                                              const float* __restrict__ bres,
                                              float* __restrict__ S,
                                              const float* __restrict__ Sin,
                                              const float* __restrict__ gw,
                                              const float* __restrict__ gb,
                                              const float* __restrict__ ga) {
  __shared__ unsigned short lds[128 * 136];  // pitch 136 breaks bank conflicts
  __shared__ float sred[2][4][128];
  __shared__ float nsc[128], nbt[128];
  const int tid = threadIdx.x;
  const int lane = tid & 63;
  const int wv = tid >> 6;
  const int quad = lane >> 4;
  const int l16 = lane & 15;
  const int rowBase = blockIdx.x * 128;

  if (NORMB && tid < 128) {
    const float invN = 1.0f / (float)N_NODES;
    float m = Sin[tid] * invN;
    float ex2 = Sin[128 + tid] * invN;
    float af = ga[tid];
    float var = fmaxf(ex2 - (2.f * af - af * af) * m * m, 0.f);
    float rstd = rsqrtf(var + 1e-5f);
    float scv = gw[tid] * rstd;
    nsc[tid] = scv;
    nbt[tid] = gb[tid] - scv * af * m;
  }

  f32x4 acc[2][8];
  f32x4 accR[2][8];
#pragma unroll
  for (int rt = 0; rt < 2; ++rt)
#pragma unroll
    for (int c = 0; c < 8; ++c) {
      acc[rt][c] = (f32x4){0.f, 0.f, 0.f, 0.f};
      if (FUSERES) accR[rt][c] = (f32x4){0.f, 0.f, 0.f, 0.f};
    }

  for (int ii = 0; ii < 2; ++ii) {
    const unsigned short* Ain = (ii == 0) ? A : B;
    const unsigned short* Win = (ii == 0) ? W1 : W2;
    __syncthreads();
    const uint4* A4 = (const uint4*)Ain;
    for (int idx = tid; idx < 128 * 16; idx += 256) {
      int r = idx >> 4, c = idx & 15;
      int gr = rowBase + r;
      uint4 v = make_uint4(0u, 0u, 0u, 0u);
      if (gr < N_NODES) v = A4[gr * 16 + c];
      if (NORMB && ii == 1) {
        unsigned int* pv = (unsigned int*)&v;
#pragma unroll
        for (int h = 0; h < 4; ++h) {
          int f0 = c * 8 + 2 * h;
          float lo = fmaxf(nsc[f0] * bf2f((unsigned short)(pv[h] & 0xffffu)) + nbt[f0], 0.f);
          float hi = fmaxf(nsc[f0 + 1] * bf2f((unsigned short)(pv[h] >> 16)) + nbt[f0 + 1], 0.f);
          pv[h] = (unsigned)f2bf(lo) | ((unsigned)f2bf(hi) << 16);
        }
      }
      *((uint4*)&lds[r * 136 + c * 8]) = v;
    }
    __syncthreads();
#pragma unroll
    for (int ks = 0; ks < 4; ++ks) {
      bf16x8 a0 = *((const bf16x8*)&lds[(wv * 32 + l16) * 136 + ks * 32 + quad * 8]);
      bf16x8 a1 = *((const bf16x8*)&lds[(wv * 32 + 16 + l16) * 136 + ks * 32 + quad * 8]);
#pragma unroll
      for (int c = 0; c < 8; ++c) {
        bf16x8 b = *((const bf16x8*)&Win[(c * 16 + l16) * 128 + ks * 32 + quad * 8]);
        acc[0][c] = __builtin_amdgcn_mfma_f32_16x16x32_bf16(a0, b, acc[0][c], 0, 0, 0);
        acc[1][c] = __builtin_amdgcn_mfma_f32_16x16x32_bf16(a1, b, acc[1][c], 0, 0, 0);
        if (FUSERES && ii == 1) {
          bf16x8 br = *((const bf16x8*)&Wres[(c * 16 + l16) * 128 + ks * 32 + quad * 8]);
          accR[0][c] = __builtin_amdgcn_mfma_f32_16x16x32_bf16(a0, br, accR[0][c], 0, 0, 0);
          accR[1][c] = __builtin_amdgcn_mfma_f32_16x16x32_bf16(a1, br, accR[1][c], 0, 0, 0);
        }
      }
    }
  }

  float p1[8], p2[8];
#pragma unroll
  for (int c = 0; c < 8; ++c) { p1[c] = 0.f; p2[c] = 0.f; }
#pragma unroll
  for (int c = 0; c < 8; ++c) {
    int col = c * 16 + l16;
    float bv = bias[col];
    float bvR = FUSERES ? bres[col] : 0.f;
#pragma unroll
    for (int rt = 0; rt < 2; ++rt) {
#pragma unroll
      for (int g = 0; g < 4; ++g) {
        int row = rowBase + wv * 32 + rt * 16 + quad * 4 + g;
        if (row < N_NODES) {
          float v = acc[rt][c][g] + bv;
          ((unsigned short*)outv)[row * 128 + col] = f2bf(v);
          p1[c] += v;
          p2[c] += v * v;
          if (FUSERES) outres[row * 128 + col] = accR[rt][c][g] + bvR;
        }
      }
    }
  }
#pragma unroll
  for (int c = 0; c < 8; ++c) {
    p1[c] += __shfl_xor(p1[c], 16); p1[c] += __shfl_xor(p1[c], 32);
    p2[c] += __shfl_xor(p2[c], 16); p2[c] += __shfl_xor(p2[c], 32);
  }
  if (quad == 0) {
#pragma unroll
    for (int c = 0; c < 8; ++c) {
      sred[0][wv][c * 16 + l16] = p1[c];
      sred[1][wv][c * 16 + l16] = p2[c];
    }
  }
  __syncthreads();
  if (tid < 128) {
    atomicAdd(&S[tid], sred[0][0][tid] + sred[0][1][tid] + sred[0][2][tid] + sred[0][3][tid]);
  } else {
    int f = tid - 128;
    atomicAdd(&S[128 + f], sred[1][0][f] + sred[1][1][f] + sred[1][2][f] + sred[1][3][f]);
  }
}

// ---- final GraphNorm + ReLU + residual accumulate (fp32 out) ------------
__global__ __launch_bounds__(256) void k_norm2(const unsigned short* __restrict__ pre,
                                               const float* __restrict__ S,
                                               const float* __restrict__ w,
                                               const float* __restrict__ b,
                                               const float* __restrict__ a,
                                               float* __restrict__ outp) {
  int f = threadIdx.x & 127;
  const float invN = 1.0f / (float)N_NODES;
  float m = S[f] * invN;
  float ex2 = S[128 + f] * invN;
  float af = a[f];
  float var = fmaxf(ex2 - (2.f * af - af * af) * m * m, 0.f);
  float rstd = rsqrtf(var + 1e-5f);
  float wf = w[f];
  float bv = b[f];
  float shift = af * m;
  int rowStart = blockIdx.x * 2 + (threadIdx.x >> 7);
  for (int r = rowStart; r < N_NODES; r += gridDim.x * 2) {
    int idx = r * 128 + f;
    float v = bf2f(pre[idx]);
    float o = fmaxf(wf * (v - shift) * rstd + bv, 0.f);
    outp[idx] = o + outp[idx];
  }
}

extern "C" void kernel_launch(void* const* d_in, const int* in_sizes, int n_in,
                              void* d_out, int out_size, void* d_ws, size_t ws_size,
                              hipStream_t stream) {
  const float* x = (const float*)d_in[0];
  const int* ei = (const int*)d_in[1];
  const float* Wl1 = (const float*)d_in[2];
  const float* bl1 = (const float*)d_in[3];
  const float* Wr1 = (const float*)d_in[4];
  const float* Wl2 = (const float*)d_in[5];
  const float* bl2 = (const float*)d_in[6];
  const float* Wr2 = (const float*)d_in[7];
  const float* g1w = (const float*)d_in[8];
  const float* g1b = (const float*)d_in[9];
  const float* g1a = (const float*)d_in[10];
  const float* g2w = (const float*)d_in[11];
  const float* g2b = (const float*)d_in[12];
  const float* g2a = (const float*)d_in[13];
  const float* Wres = (const float*)d_in[14];
  const float* bres = (const float*)d_in[15];

  char* w = (char*)d_ws;
  const size_t FEATB = (size_t)N_NODES * D * 2;  // 12.8 MB bf16 buffer
  unsigned short* xb = (unsigned short*)(w);
  unsigned short* buf0 = (unsigned short*)(w + FEATB);
  unsigned short* agg = (unsigned short*)(w + 2 * FEATB);
  char* ip = w + 3 * FEATB;
  int* bcnt = (int*)ip;                                  // 512 B
  float* stats = (float*)(ip + 512);                     // 2048 B
  int* flag = (int*)(ip + 2560);                         // 16 B
  int* bbase = (int*)(ip + 2576);                        // 512 B (99 used)
  int* cursor = (int*)(ip + 3088);                       // 512 B
  int* off = (int*)(ip + 3600);                          // 200016 B
  unsigned short* srcs = (unsigned short*)(ip + 203616); // 1.6 MB
  unsigned short* wb = (unsigned short*)(ip + 1803616);  // 163840 B
  const size_t NEED = 3 * FEATB + 1967456;
  unsigned int* binned = (unsigned int*)agg;  // aliases agg; used pre-agg only

  float* outp = (float*)d_out;

  if (ws_size < NEED) {  // diagnostic: finite wrong answer instead of NaN
    hipMemsetAsync(d_out, 0, (size_t)out_size * 4, stream);
    return;
  }

  unsigned short* wl1b = wb;
  unsigned short* wr1b = wb + 16384;
  unsigned short* wl2b = wb + 32768;
  unsigned short* wr2b = wb + 49152;
  unsigned short* wresb = wb + 65536;

  k_detect<<<1, 256, 0, stream>>>(ei, flag, bcnt, stats);
  k_cast<<<(N_NODES * D / 4 + 255) / 256, 256, 0, stream>>>(x, xb, N_NODES * D / 4);
  k_castw<<<80, 256, 0, stream>>>(Wl1, Wr1, Wl2, Wr2, Wres, wb);

  // bucketed CSR build
  k_binA0<<<NBKT, 256, 0, stream>>>(ei, flag, bcnt);
  k_scanS<<<1, 128, 0, stream>>>(bcnt, bbase, cursor, off);
  k_binA1<<<NBKT, 256, 0, stream>>>(ei, flag, cursor, binned);
  k_pass2<<<NBKT, 256, 0, stream>>>(bbase, binned, off, srcs);

  const int GEMM_GRID = (N_NODES + 127) / 128;

  // layer 1: agg -> fused [conv GEMM + stats | residual GEMM]
  k_agg<false><<<(N_NODES + 3) / 4, 256, 0, stream>>>(xb, off, srcs, nullptr, nullptr,
                                                      nullptr, nullptr, agg);
  k_gemm<true, false><<<GEMM_GRID, 256, 0, stream>>>(agg, wl1b, xb, wr1b, wresb, bl1,
                                                     buf0, outp, bres, stats,
                                                     nullptr, nullptr, nullptr, nullptr);

  // layer 2: norm1 fused into agg gather + gemm2 B-staging
  k_agg<true><<<(N_NODES + 3) / 4, 256, 0, stream>>>(buf0, off, srcs, stats, g1w, g1b,
                                                     g1a, agg);
  k_gemm<false, true><<<GEMM_GRID, 256, 0, stream>>>(agg, wl2b, buf0, wr2b, nullptr, bl2,
                                                     agg, nullptr, nullptr, stats + 256,
                                                     stats, g1w, g1b, g1a);
  k_norm2<<<1024, 256, 0, stream>>>(agg, stats + 256, g2w, g2b, g2a, outp);
}